// Round 6
// baseline (75.715 us; speedup 1.0000x reference)
//
#include <hip/hip_runtime.h>
#include <hip/hip_fp16.h>
#include <math.h>

#define NF   30
#define NP   435          // C(30,2)
#define NPAD 448          // 14 tiles of 32 pairs
#define NT   14
#define DIM  64
#define ATT  32
#define BPB  4            // one batch element per wave

typedef __attribute__((ext_vector_type(8)))  _Float16 half8v;
typedef __attribute__((ext_vector_type(16))) float    f32x16;

// compile-time pair table: p -> (i | j<<8), padded with (31,31) -> zero rows
struct IJTab { unsigned short v[NPAD]; };
static constexpr IJTab make_ij() {
    IJTab t{};
    int p = 0;
    for (int i = 0; i < NF; ++i)
        for (int j = i + 1; j < NF; ++j)
            t.v[p++] = (unsigned short)(i | (j << 8));
    for (; p < NPAD; ++p) t.v[p] = (unsigned short)(31 | (31 << 8));
    return t;
}
__constant__ IJTab IJ = make_ij();

// XOR-swizzled layouts: 16B block index ^= (row&7) -> all rows 128B/64B apart,
// every 16B chunk aligned, banks spread across rows (T2 pattern).
__device__ __forceinline__ int eh_off(int row, int d) {      // Eh logical [32][64]
    return (row << 6) + ((((d >> 3) ^ (row & 7)) << 3) | (d & 7));
}
__device__ __forceinline__ int ua_off(int i, int j) {        // UA logical [32][32]
    return (i << 5) + ((((j >> 3) ^ (i & 7)) << 3) | (j & 7));
}

struct __align__(16) WaveCtx {
    _Float16 Eh[32 * 64];   // 4096 B (rows 30,31 zero)
    _Float16 UA[32 * 32];   // 2048 B upper-tri attention exp (unnormalized)
    float    pooled[DIM];   // 256 B
    float    h1[32];        // 128 B
    float    h2[16];        // 64 B
};                          // 6592 B -> 26368 B/block -> 6 blocks/CU

__launch_bounds__(256, 6)
__global__ void afm_wave_kernel(const int*   __restrict__ x,
                                const float* __restrict__ emb,
                                const float* __restrict__ W,     // [64][32]
                                const float* __restrict__ bb,    // [32]
                                const float* __restrict__ hh,    // [32]
                                const float* __restrict__ d1w,   // [32][64]
                                const float* __restrict__ d1b,   // [32]
                                const float* __restrict__ d2w,   // [16][32]
                                const float* __restrict__ d2b,   // [16]
                                const float* __restrict__ fw,    // [16]
                                const float* __restrict__ fb,    // [1]
                                float* __restrict__ out,
                                int Btot)
{
    __shared__ WaveCtx ctx[BPB];

    const int t    = threadIdx.x;
    const int lane = t & 63;
    const int w    = t >> 6;
    const int col  = lane & 31;
    const int half = lane >> 5;
    const int b    = blockIdx.x * BPB + w;

    if (b >= Btot) return;           // no cross-wave cooperation -> safe early out
    WaveCtx& C = ctx[w];

    // ---- phase 0: E gather -> swizzled fp16 LDS; zero UA (no barriers anywhere) ----
    #pragma unroll
    for (int it = 0; it < 4; ++it) {
        const int s = it * 64 + lane;
        const int row = s >> 3, blk = s & 7;
        half8v v8 = {};
        if (row < NF) {
            const int xr = x[b * NF + row];
            const float4 f0 = *(const float4*)&emb[(long)xr * DIM + blk * 8];
            const float4 f1 = *(const float4*)&emb[(long)xr * DIM + blk * 8 + 4];
            v8[0] = (_Float16)f0.x; v8[1] = (_Float16)f0.y;
            v8[2] = (_Float16)f0.z; v8[3] = (_Float16)f0.w;
            v8[4] = (_Float16)f1.x; v8[5] = (_Float16)f1.y;
            v8[6] = (_Float16)f1.z; v8[7] = (_Float16)f1.w;
        }
        *(half8v*)&C.Eh[(row << 6) + ((blk ^ (row & 7)) << 3)] = v8;   // one b128 store
    }
    {   // zero UA: 2048 B = 128 x float4
        const float4 z = make_float4(0.f, 0.f, 0.f, 0.f);
        ((float4*)C.UA)[lane]      = z;
        ((float4*)C.UA)[lane + 64] = z;
    }

    // ---- A-fragments (W^T) straight from global (coalesced, L1-hot) ----
    half8v wfrag[4];
    #pragma unroll
    for (int ks = 0; ks < 4; ++ks) {
        #pragma unroll
        for (int e = 0; e < 8; ++e)
            wfrag[ks][e] = (_Float16)W[(ks * 16 + half * 8 + e) * ATT + col];
    }

    // bias/h fragments: C-row r -> a = (r&3) + 8*(r>>2) + 4*half
    float4 b4[4], h4[4];
    #pragma unroll
    for (int q = 0; q < 4; ++q) {
        b4[q] = *(const float4*)&bb[8 * q + 4 * half];
        h4[q] = *(const float4*)&hh[8 * q + 4 * half];
    }

    // ---- phase 1: 14 tiles; C[a][p]=sum_d W[d][a]*(e_i[d]*e_j[d]); fused exp->UA ----
    float wsum = 0.f;
    #pragma unroll 2
    for (int tile = 0; tile < NT; ++tile) {
        const int p  = tile * 32 + col;
        const int pj = IJ.v[p];
        const int fi = pj & 255, fj = pj >> 8;
        const _Float16* Ei = &C.Eh[fi << 6];
        const _Float16* Ej = &C.Eh[fj << 6];
        const int si = fi & 7, sj = fj & 7;
        f32x16 acc = {};
        #pragma unroll
        for (int ks = 0; ks < 4; ++ks) {
            const int blk = 2 * ks + half;                       // d0 >> 3
            const half8v va = *(const half8v*)&Ei[(blk ^ si) << 3];  // ds_read_b128
            const half8v vc = *(const half8v*)&Ej[(blk ^ sj) << 3];  // ds_read_b128
            const half8v bp = va * vc;                           // 4x v_pk_mul_f16
            acc = __builtin_amdgcn_mfma_f32_32x32x16_f16(wfrag[ks], bp, acc, 0, 0, 0);
        }
        float sv = 0.f;
        #pragma unroll
        for (int q = 0; q < 4; ++q) {
            sv += fmaxf(acc[4 * q + 0] + b4[q].x, 0.f) * h4[q].x;
            sv += fmaxf(acc[4 * q + 1] + b4[q].y, 0.f) * h4[q].y;
            sv += fmaxf(acc[4 * q + 2] + b4[q].z, 0.f) * h4[q].z;
            sv += fmaxf(acc[4 * q + 3] + b4[q].w, 0.f) * h4[q].w;
        }
        sv += __shfl_xor(sv, 32);
        // |s| <~ 0.2 by construction -> exp without max-subtract (validated R3-R5)
        if (half == 0 && p < NP) {
            const float ex = __expf(sv);
            C.UA[ua_off(fi, fj)] = (_Float16)ex;
            wsum += ex;
        }
    }
    #pragma unroll
    for (int o = 1; o <= 16; o <<= 1) wsum += __shfl_xor(wsum, o);
    const float inv_sum = 1.f / wsum;                // valid on half==0 lanes

    // ---- phase 3: T = UA @ E; pooled[d] = inv_sum * sum_i E[i][d]*T[i][d] ----
    half8v uaf[2];
    #pragma unroll
    for (int ks = 0; ks < 2; ++ks)
        uaf[ks] = *(const half8v*)&C.UA[(col << 5) + (((2 * ks + half) ^ (col & 7)) << 3)];
    #pragma unroll
    for (int dh = 0; dh < 2; ++dh) {
        const int d = col + 32 * dh;
        f32x16 tacc = {};
        #pragma unroll
        for (int ks = 0; ks < 2; ++ks) {
            const int j0 = ks * 16 + half * 8;
            half8v eb;
            #pragma unroll
            for (int e = 0; e < 8; ++e) eb[e] = C.Eh[eh_off(j0 + e, d)];  // column read
            tacc = __builtin_amdgcn_mfma_f32_32x32x16_f16(uaf[ks], eb, tacc, 0, 0, 0);
        }
        float sv = 0.f;
        #pragma unroll
        for (int q = 0; q < 4; ++q) {
            const int i0 = 8 * q + 4 * half;
            #pragma unroll
            for (int s = 0; s < 4; ++s)
                sv += (float)C.Eh[eh_off(i0 + s, d)] * tacc[4 * q + s];
        }
        sv += __shfl_xor(sv, 32);
        if (half == 0) C.pooled[d] = sv * inv_sum;
    }

    // ---- phase 4: MLP 64->32->16->1 in-wave (within-wave LDS ordering) ----
    {   // d1: 32 outputs x 2 lanes
        const int o = lane >> 1, part = lane & 1;
        const float* wr = &d1w[o * DIM + part * 32];
        const float* pp = &C.pooled[part * 32];
        float a1 = 0.f;
        #pragma unroll
        for (int k = 0; k < 32; ++k) a1 = fmaf(pp[k], wr[k], a1);
        a1 += __shfl_xor(a1, 1);
        if (part == 0) C.h1[o] = fmaxf(a1 + d1b[o], 0.f);
    }
    {   // d2: 16 outputs x 4 lanes
        const int o = lane >> 2, part = lane & 3;
        float a2 = 0.f;
        #pragma unroll
        for (int k = 0; k < 8; ++k)
            a2 = fmaf(C.h1[part * 8 + k], d2w[o * 32 + part * 8 + k], a2);
        a2 += __shfl_xor(a2, 1);
        a2 += __shfl_xor(a2, 2);
        if (part == 0) C.h2[o] = fmaxf(a2 + d2b[o], 0.f);
    }
    if (lane < 16) {
        float v = C.h2[lane] * fw[lane];
        #pragma unroll
        for (int o2 = 1; o2 < 16; o2 <<= 1) v += __shfl_xor(v, o2);
        if (lane == 0) out[b] = 1.f / (1.f + __expf(-(v + fb[0])));
    }
}

extern "C" void kernel_launch(void* const* d_in, const int* in_sizes, int n_in,
                              void* d_out, int out_size, void* d_ws, size_t ws_size,
                              hipStream_t stream) {
    (void)n_in; (void)d_ws; (void)ws_size; (void)out_size;
    const int*   x   = (const int*)  d_in[0];
    const float* emb = (const float*)d_in[1];
    const float* W   = (const float*)d_in[2];
    const float* bbp = (const float*)d_in[3];
    const float* hhp = (const float*)d_in[4];
    const float* d1w = (const float*)d_in[5];
    const float* d1b = (const float*)d_in[6];
    const float* d2w = (const float*)d_in[7];
    const float* d2b = (const float*)d_in[8];
    const float* fw  = (const float*)d_in[9];
    const float* fb  = (const float*)d_in[10];
    float* out = (float*)d_out;

    const int B = in_sizes[0] / NF;
    const int grid = (B + BPB - 1) / BPB;
    afm_wave_kernel<<<grid, 256, 0, stream>>>(x, emb, W, bbp, hhp,
                                              d1w, d1b, d2w, d2b, fw, fb, out, B);
}

// Round 7
// 44.826 us; speedup vs baseline: 1.6891x; 1.6891x over previous
//
#include <hip/hip_runtime.h>
#include <hip/hip_fp16.h>
#include <math.h>

#define NF   30
#define NP   435          // C(30,2)
#define NPAD 448          // 14 tiles of 32 pairs
#define NT   14
#define DIM  64
#define ATT  32
#define WAS  40           // Wt row stride (fp16): 80B, rows 16B-aligned
#define BPB  4            // one batch element per wave

typedef __attribute__((ext_vector_type(8)))  _Float16 half8v;
typedef __attribute__((ext_vector_type(16))) float    f32x16;

// compile-time pair table: p -> (i | j<<8), padded with (31,31) -> zero rows
struct IJTab { unsigned short v[NPAD]; };
static constexpr IJTab make_ij() {
    IJTab t{};
    int p = 0;
    for (int i = 0; i < NF; ++i)
        for (int j = i + 1; j < NF; ++j)
            t.v[p++] = (unsigned short)(i | (j << 8));
    for (; p < NPAD; ++p) t.v[p] = (unsigned short)(31 | (31 << 8));
    return t;
}
__constant__ IJTab IJ = make_ij();

// XOR-swizzled layouts: 16B block index ^= (row&7) -> rows 128B apart, every
// 16B chunk aligned (ds_read_b128), banks spread across rows (T2 pattern).
__device__ __forceinline__ int eh_off(int row, int d) {      // Eh logical [32][64]
    return (row << 6) + ((((d >> 3) ^ (row & 7)) << 3) | (d & 7));
}
__device__ __forceinline__ int ua_off(int i, int j) {        // UA logical [32][32]
    return (i << 5) + ((((j >> 3) ^ (i & 7)) << 3) | (j & 7));
}

struct __align__(16) WaveCtx {
    _Float16 Eh[32 * 64];   // 4096 B (rows 30,31 zero)
    _Float16 UA[32 * 32];   // 2048 B upper-tri attention exp (unnormalized)
    float    pooled[DIM];   // 256 B
    float    h1[32];        // 128 B
    float    h2[16];        // 64 B
};                          // 6592 B; x4 + Wt 2560 = 28928 B/block -> 5 blocks/CU

__launch_bounds__(256, 5)
__global__ void afm_wave_kernel(const int*   __restrict__ x,
                                const float* __restrict__ emb,
                                const float* __restrict__ W,     // [64][32]
                                const float* __restrict__ bb,    // [32]
                                const float* __restrict__ hh,    // [32]
                                const float* __restrict__ d1w,   // [32][64]
                                const float* __restrict__ d1b,   // [32]
                                const float* __restrict__ d2w,   // [16][32]
                                const float* __restrict__ d2b,   // [16]
                                const float* __restrict__ fw,    // [16]
                                const float* __restrict__ fb,    // [1]
                                float* __restrict__ out,
                                int Btot)
{
    __shared__ WaveCtx ctx[BPB];
    __shared__ __align__(16) _Float16 Wt[32][WAS];  // W^T fp16, shared across waves

    const int t    = threadIdx.x;
    const int lane = t & 63;
    const int w    = t >> 6;
    const int col  = lane & 31;
    const int half = lane >> 5;
    const int b    = blockIdx.x * BPB + w;

    WaveCtx& C = ctx[w];

    // ---- phase 0: cooperative W^T stage + per-wave E gather / UA zero ----
    {   // W^T -> Wt fp16 (block-cooperative; ds_write_b128 per thread)
        const int a = t >> 3, kb = (t & 7) * 8;
        half8v w8;
        #pragma unroll
        for (int e = 0; e < 8; ++e) w8[e] = (_Float16)W[(kb + e) * ATT + a];
        *(half8v*)&Wt[a][kb] = w8;
    }
    if (b < Btot) {
        // E gather -> swizzled fp16 LDS; rows 30,31 zero
        #pragma unroll
        for (int it = 0; it < 4; ++it) {
            const int s = it * 64 + lane;
            const int row = s >> 3, blk = s & 7;
            half8v v8 = {};
            if (row < NF) {
                const int xr = x[b * NF + row];
                const float4 f0 = *(const float4*)&emb[(long)xr * DIM + blk * 8];
                const float4 f1 = *(const float4*)&emb[(long)xr * DIM + blk * 8 + 4];
                v8[0] = (_Float16)f0.x; v8[1] = (_Float16)f0.y;
                v8[2] = (_Float16)f0.z; v8[3] = (_Float16)f0.w;
                v8[4] = (_Float16)f1.x; v8[5] = (_Float16)f1.y;
                v8[6] = (_Float16)f1.z; v8[7] = (_Float16)f1.w;
            }
            *(half8v*)&C.Eh[(row << 6) + ((blk ^ (row & 7)) << 3)] = v8;  // b128 store
        }
        // zero UA: 2048 B = 128 x float4
        const float4 z = make_float4(0.f, 0.f, 0.f, 0.f);
        ((float4*)C.UA)[lane]      = z;
        ((float4*)C.UA)[lane + 64] = z;
    }
    __syncthreads();                                 // the ONLY barrier (Wt)

    if (b >= Btot) return;

    // A-fragments (W^T) from LDS: one ds_read_b128 each (register-resident)
    half8v wfrag[4];
    #pragma unroll
    for (int ks = 0; ks < 4; ++ks)
        wfrag[ks] = *(const half8v*)&Wt[col][ks * 16 + half * 8];

    // bias/h fragments: C-row r -> a = (r&3) + 8*(r>>2) + 4*half
    float4 b4[4], h4[4];
    #pragma unroll
    for (int q = 0; q < 4; ++q) {
        b4[q] = *(const float4*)&bb[8 * q + 4 * half];
        h4[q] = *(const float4*)&hh[8 * q + 4 * half];
    }

    // ---- phase 1: 14 tiles; C[a][p]=sum_d W[d][a]*(e_i[d]*e_j[d]); fused exp->UA ----
    float wsum = 0.f;
    #pragma unroll 2
    for (int tile = 0; tile < NT; ++tile) {
        const int p  = tile * 32 + col;
        const int pj = IJ.v[p];
        const int fi = pj & 255, fj = pj >> 8;
        const _Float16* Ei = &C.Eh[fi << 6];
        const _Float16* Ej = &C.Eh[fj << 6];
        const int si = fi & 7, sj = fj & 7;
        f32x16 acc = {};
        #pragma unroll
        for (int ks = 0; ks < 4; ++ks) {
            const int blk = 2 * ks + half;                           // d0 >> 3
            const half8v va = *(const half8v*)&Ei[(blk ^ si) << 3];  // ds_read_b128
            const half8v vc = *(const half8v*)&Ej[(blk ^ sj) << 3];  // ds_read_b128
            const half8v bp = va * vc;                               // 4x v_pk_mul_f16
            acc = __builtin_amdgcn_mfma_f32_32x32x16_f16(wfrag[ks], bp, acc, 0, 0, 0);
        }
        float sv = 0.f;
        #pragma unroll
        for (int q = 0; q < 4; ++q) {
            sv += fmaxf(acc[4 * q + 0] + b4[q].x, 0.f) * h4[q].x;
            sv += fmaxf(acc[4 * q + 1] + b4[q].y, 0.f) * h4[q].y;
            sv += fmaxf(acc[4 * q + 2] + b4[q].z, 0.f) * h4[q].z;
            sv += fmaxf(acc[4 * q + 3] + b4[q].w, 0.f) * h4[q].w;
        }
        sv += __shfl_xor(sv, 32);
        // |s| <~ 0.2 by construction -> exp without max-subtract (validated R3-R6)
        if (half == 0 && p < NP) {
            const float ex = __expf(sv);
            C.UA[ua_off(fi, fj)] = (_Float16)ex;
            wsum += ex;
        }
    }
    #pragma unroll
    for (int o = 1; o <= 16; o <<= 1) wsum += __shfl_xor(wsum, o);
    const float inv_sum = 1.f / wsum;                // valid on half==0 lanes

    // ---- phase 3: T = UA @ E; pooled[d] = inv_sum * sum_i E[i][d]*T[i][d] ----
    half8v uaf[2];
    #pragma unroll
    for (int ks = 0; ks < 2; ++ks)
        uaf[ks] = *(const half8v*)&C.UA[(col << 5) + (((2 * ks + half) ^ (col & 7)) << 3)];
    #pragma unroll
    for (int dh = 0; dh < 2; ++dh) {
        const int d = col + 32 * dh;
        f32x16 tacc = {};
        #pragma unroll
        for (int ks = 0; ks < 2; ++ks) {
            const int j0 = ks * 16 + half * 8;
            half8v eb;
            #pragma unroll
            for (int e = 0; e < 8; ++e) eb[e] = C.Eh[eh_off(j0 + e, d)];  // column read
            tacc = __builtin_amdgcn_mfma_f32_32x32x16_f16(uaf[ks], eb, tacc, 0, 0, 0);
        }
        float sv = 0.f;
        #pragma unroll
        for (int q = 0; q < 4; ++q) {
            const int i0 = 8 * q + 4 * half;
            #pragma unroll
            for (int s = 0; s < 4; ++s)
                sv += (float)C.Eh[eh_off(i0 + s, d)] * tacc[4 * q + s];
        }
        sv += __shfl_xor(sv, 32);
        if (half == 0) C.pooled[d] = sv * inv_sum;
    }

    // ---- phase 4: MLP 64->32->16->1 in-wave (within-wave LDS ordering) ----
    {   // d1: 32 outputs x 2 lanes
        const int o = lane >> 1, part = lane & 1;
        const float* wr = &d1w[o * DIM + part * 32];
        const float* pp = &C.pooled[part * 32];
        float a1 = 0.f;
        #pragma unroll
        for (int k = 0; k < 32; ++k) a1 = fmaf(pp[k], wr[k], a1);
        a1 += __shfl_xor(a1, 1);
        if (part == 0) C.h1[o] = fmaxf(a1 + d1b[o], 0.f);
    }
    {   // d2: 16 outputs x 4 lanes
        const int o = lane >> 2, part = lane & 3;
        float a2 = 0.f;
        #pragma unroll
        for (int k = 0; k < 8; ++k)
            a2 = fmaf(C.h1[part * 8 + k], d2w[o * 32 + part * 8 + k], a2);
        a2 += __shfl_xor(a2, 1);
        a2 += __shfl_xor(a2, 2);
        if (part == 0) C.h2[o] = fmaxf(a2 + d2b[o], 0.f);
    }
    if (lane < 16) {
        float v = C.h2[lane] * fw[lane];
        #pragma unroll
        for (int o2 = 1; o2 < 16; o2 <<= 1) v += __shfl_xor(v, o2);
        if (lane == 0) out[b] = 1.f / (1.f + __expf(-(v + fb[0])));
    }
}

extern "C" void kernel_launch(void* const* d_in, const int* in_sizes, int n_in,
                              void* d_out, int out_size, void* d_ws, size_t ws_size,
                              hipStream_t stream) {
    (void)n_in; (void)d_ws; (void)ws_size; (void)out_size;
    const int*   x   = (const int*)  d_in[0];
    const float* emb = (const float*)d_in[1];
    const float* W   = (const float*)d_in[2];
    const float* bbp = (const float*)d_in[3];
    const float* hhp = (const float*)d_in[4];
    const float* d1w = (const float*)d_in[5];
    const float* d1b = (const float*)d_in[6];
    const float* d2w = (const float*)d_in[7];
    const float* d2b = (const float*)d_in[8];
    const float* fw  = (const float*)d_in[9];
    const float* fb  = (const float*)d_in[10];
    float* out = (float*)d_out;

    const int B = in_sizes[0] / NF;
    const int grid = (B + BPB - 1) / BPB;
    afm_wave_kernel<<<grid, 256, 0, stream>>>(x, emb, W, bbp, hhp,
                                              d1w, d1b, d2w, d2b, fw, fb, out, B);
}

// Round 8
// 43.779 us; speedup vs baseline: 1.7295x; 1.0239x over previous
//
#include <hip/hip_runtime.h>
#include <hip/hip_fp16.h>
#include <math.h>

#define NF   30
#define NP   435          // C(30,2)
#define NPAD 448          // 14 tiles of 32 pairs
#define NT   14
#define DIM  64
#define ATT  32
#define WAS  40           // Wt row stride (fp16): 80B, rows 16B-aligned
#define BPB  4            // one batch element per wave

typedef __attribute__((ext_vector_type(8)))  _Float16 half8v;
typedef __attribute__((ext_vector_type(16))) float    f32x16;

// compile-time pair table: p -> (i | j<<8), padded with (31,31) -> zero rows
struct IJTab { unsigned short v[NPAD]; };
static constexpr IJTab make_ij() {
    IJTab t{};
    int p = 0;
    for (int i = 0; i < NF; ++i)
        for (int j = i + 1; j < NF; ++j)
            t.v[p++] = (unsigned short)(i | (j << 8));
    for (; p < NPAD; ++p) t.v[p] = (unsigned short)(31 | (31 << 8));
    return t;
}
__constant__ IJTab IJ = make_ij();

// XOR-swizzled layouts: 16B block index ^= (row&7) -> rows 128B apart, every
// 16B chunk aligned (ds_read_b128), banks spread across rows (T2 pattern).
__device__ __forceinline__ int eh_off(int row, int d) {      // Eh logical [32][64]
    return (row << 6) + ((((d >> 3) ^ (row & 7)) << 3) | (d & 7));
}
__device__ __forceinline__ int ua_off(int i, int j) {        // UA logical [32][32]
    return (i << 5) + ((((j >> 3) ^ (i & 7)) << 3) | (j & 7));
}

struct __align__(16) WaveCtx {
    _Float16 Eh[32 * 64];   // 4096 B (rows 30,31 zero)
    _Float16 UA[32 * 32];   // 2048 B upper-tri attention exp (unnormalized)
    float    pooled[DIM];   // 256 B
    float    h1[32];        // 128 B
    float    h2[16];        // 64 B
};                          // 6592 B; x4 + Wt 2560 = 28928 B/block -> 5 blocks/CU

__launch_bounds__(256, 4)   // VGPR cap 128: room for 2 accumulators, no spill
__global__ void afm_wave_kernel(const int*   __restrict__ x,
                                const float* __restrict__ emb,
                                const float* __restrict__ W,     // [64][32]
                                const float* __restrict__ bb,    // [32]
                                const float* __restrict__ hh,    // [32]
                                const float* __restrict__ d1w,   // [32][64]
                                const float* __restrict__ d1b,   // [32]
                                const float* __restrict__ d2w,   // [16][32]
                                const float* __restrict__ d2b,   // [16]
                                const float* __restrict__ fw,    // [16]
                                const float* __restrict__ fb,    // [1]
                                float* __restrict__ out,
                                int Btot)
{
    __shared__ WaveCtx ctx[BPB];
    __shared__ __align__(16) _Float16 Wt[32][WAS];  // W^T fp16, shared across waves

    const int t    = threadIdx.x;
    const int lane = t & 63;
    const int w    = t >> 6;
    const int col  = lane & 31;
    const int half = lane >> 5;
    const int b    = blockIdx.x * BPB + w;

    WaveCtx& C = ctx[w];

    // ---- phase 0: cooperative W^T stage + per-wave E gather / UA zero ----
    {   // W^T -> Wt fp16 (block-cooperative; ds_write_b128 per thread)
        const int a = t >> 3, kb = (t & 7) * 8;
        half8v w8;
        #pragma unroll
        for (int e = 0; e < 8; ++e) w8[e] = (_Float16)W[(kb + e) * ATT + a];
        *(half8v*)&Wt[a][kb] = w8;
    }
    if (b < Btot) {
        // E gather -> swizzled fp16 LDS; rows 30,31 zero
        #pragma unroll
        for (int it = 0; it < 4; ++it) {
            const int s = it * 64 + lane;
            const int row = s >> 3, blk = s & 7;
            half8v v8 = {};
            if (row < NF) {
                const int xr = x[b * NF + row];
                const float4 f0 = *(const float4*)&emb[(long)xr * DIM + blk * 8];
                const float4 f1 = *(const float4*)&emb[(long)xr * DIM + blk * 8 + 4];
                v8[0] = (_Float16)f0.x; v8[1] = (_Float16)f0.y;
                v8[2] = (_Float16)f0.z; v8[3] = (_Float16)f0.w;
                v8[4] = (_Float16)f1.x; v8[5] = (_Float16)f1.y;
                v8[6] = (_Float16)f1.z; v8[7] = (_Float16)f1.w;
            }
            *(half8v*)&C.Eh[(row << 6) + ((blk ^ (row & 7)) << 3)] = v8;  // b128 store
        }
        // zero UA: 2048 B = 128 x float4
        const float4 z = make_float4(0.f, 0.f, 0.f, 0.f);
        ((float4*)C.UA)[lane]      = z;
        ((float4*)C.UA)[lane + 64] = z;
    }
    __syncthreads();                                 // the ONLY barrier (Wt)

    if (b >= Btot) return;

    // A-fragments (W^T) from LDS: one ds_read_b128 each (register-resident)
    half8v wfrag[4];
    #pragma unroll
    for (int ks = 0; ks < 4; ++ks)
        wfrag[ks] = *(const half8v*)&Wt[col][ks * 16 + half * 8];

    // bias/h fragments: C-row r -> a = (r&3) + 8*(r>>2) + 4*half
    float4 b4[4], h4[4];
    #pragma unroll
    for (int q = 0; q < 4; ++q) {
        b4[q] = *(const float4*)&bb[8 * q + 4 * half];
        h4[q] = *(const float4*)&hh[8 * q + 4 * half];
    }

    // ---- phase 1: 7 x (2 interleaved tiles) -> 2 independent MFMA chains ----
    float wsum = 0.f;
    for (int tp = 0; tp < 7; ++tp) {
        const int pA = tp * 64 + col;        // tile 2tp   (always < NP)
        const int pB = pA + 32;              // tile 2tp+1 (may pad at tp==6)
        const int pjA = IJ.v[pA], pjB = IJ.v[pB];
        const int fiA = pjA & 255, fjA = pjA >> 8;
        const int fiB = pjB & 255, fjB = pjB >> 8;
        const _Float16* EiA = &C.Eh[fiA << 6];
        const _Float16* EjA = &C.Eh[fjA << 6];
        const _Float16* EiB = &C.Eh[fiB << 6];
        const _Float16* EjB = &C.Eh[fjB << 6];
        const int siA = fiA & 7, sjA = fjA & 7;
        const int siB = fiB & 7, sjB = fjB & 7;
        f32x16 accA = {}, accB = {};
        #pragma unroll
        for (int ks = 0; ks < 4; ++ks) {
            const int blk = 2 * ks + half;                            // d0 >> 3
            const half8v vaA = *(const half8v*)&EiA[(blk ^ siA) << 3];
            const half8v vcA = *(const half8v*)&EjA[(blk ^ sjA) << 3];
            const half8v vaB = *(const half8v*)&EiB[(blk ^ siB) << 3];
            const half8v vcB = *(const half8v*)&EjB[(blk ^ sjB) << 3];
            accA = __builtin_amdgcn_mfma_f32_32x32x16_f16(wfrag[ks], vaA * vcA, accA, 0, 0, 0);
            accB = __builtin_amdgcn_mfma_f32_32x32x16_f16(wfrag[ks], vaB * vcB, accB, 0, 0, 0);
        }
        float svA = 0.f, svB = 0.f;
        #pragma unroll
        for (int q = 0; q < 4; ++q) {
            svA += fmaxf(accA[4 * q + 0] + b4[q].x, 0.f) * h4[q].x;
            svA += fmaxf(accA[4 * q + 1] + b4[q].y, 0.f) * h4[q].y;
            svA += fmaxf(accA[4 * q + 2] + b4[q].z, 0.f) * h4[q].z;
            svA += fmaxf(accA[4 * q + 3] + b4[q].w, 0.f) * h4[q].w;
            svB += fmaxf(accB[4 * q + 0] + b4[q].x, 0.f) * h4[q].x;
            svB += fmaxf(accB[4 * q + 1] + b4[q].y, 0.f) * h4[q].y;
            svB += fmaxf(accB[4 * q + 2] + b4[q].z, 0.f) * h4[q].z;
            svB += fmaxf(accB[4 * q + 3] + b4[q].w, 0.f) * h4[q].w;
        }
        svA += __shfl_xor(svA, 32);
        svB += __shfl_xor(svB, 32);
        // |s| <~ 0.2 by construction -> exp without max-subtract (validated R3-R7)
        if (half == 0) {
            const float exA = __expf(svA);
            C.UA[ua_off(fiA, fjA)] = (_Float16)exA;
            wsum += exA;
            if (pB < NP) {
                const float exB = __expf(svB);
                C.UA[ua_off(fiB, fjB)] = (_Float16)exB;
                wsum += exB;
            }
        }
    }
    #pragma unroll
    for (int o = 1; o <= 16; o <<= 1) wsum += __shfl_xor(wsum, o);
    const float inv_sum = 1.f / wsum;                // valid on half==0 lanes

    // ---- phase 3: T = UA @ E; pooled[d] = inv_sum * sum_i E[i][d]*T[i][d] ----
    half8v uaf[2];
    #pragma unroll
    for (int ks = 0; ks < 2; ++ks)
        uaf[ks] = *(const half8v*)&C.UA[(col << 5) + (((2 * ks + half) ^ (col & 7)) << 3)];
    #pragma unroll
    for (int dh = 0; dh < 2; ++dh) {
        const int d = col + 32 * dh;
        f32x16 tacc = {};
        #pragma unroll
        for (int ks = 0; ks < 2; ++ks) {
            const int j0 = ks * 16 + half * 8;
            half8v eb;
            #pragma unroll
            for (int e = 0; e < 8; ++e) eb[e] = C.Eh[eh_off(j0 + e, d)];  // column read
            tacc = __builtin_amdgcn_mfma_f32_32x32x16_f16(uaf[ks], eb, tacc, 0, 0, 0);
        }
        float sv = 0.f;
        #pragma unroll
        for (int q = 0; q < 4; ++q) {
            const int i0 = 8 * q + 4 * half;
            #pragma unroll
            for (int s = 0; s < 4; ++s)
                sv += (float)C.Eh[eh_off(i0 + s, d)] * tacc[4 * q + s];
        }
        sv += __shfl_xor(sv, 32);
        if (half == 0) C.pooled[d] = sv * inv_sum;
    }

    // ---- phase 4: MLP 64->32->16->1 in-wave (within-wave LDS ordering) ----
    {   // d1: 32 outputs x 2 lanes
        const int o = lane >> 1, part = lane & 1;
        const float* wr = &d1w[o * DIM + part * 32];
        const float* pp = &C.pooled[part * 32];
        float a1 = 0.f;
        #pragma unroll
        for (int k = 0; k < 32; ++k) a1 = fmaf(pp[k], wr[k], a1);
        a1 += __shfl_xor(a1, 1);
        if (part == 0) C.h1[o] = fmaxf(a1 + d1b[o], 0.f);
    }
    {   // d2: 16 outputs x 4 lanes
        const int o = lane >> 2, part = lane & 3;
        float a2 = 0.f;
        #pragma unroll
        for (int k = 0; k < 8; ++k)
            a2 = fmaf(C.h1[part * 8 + k], d2w[o * 32 + part * 8 + k], a2);
        a2 += __shfl_xor(a2, 1);
        a2 += __shfl_xor(a2, 2);
        if (part == 0) C.h2[o] = fmaxf(a2 + d2b[o], 0.f);
    }
    if (lane < 16) {
        float v = C.h2[lane] * fw[lane];
        #pragma unroll
        for (int o2 = 1; o2 < 16; o2 <<= 1) v += __shfl_xor(v, o2);
        if (lane == 0) out[b] = 1.f / (1.f + __expf(-(v + fb[0])));
    }
}

extern "C" void kernel_launch(void* const* d_in, const int* in_sizes, int n_in,
                              void* d_out, int out_size, void* d_ws, size_t ws_size,
                              hipStream_t stream) {
    (void)n_in; (void)d_ws; (void)ws_size; (void)out_size;
    const int*   x   = (const int*)  d_in[0];
    const float* emb = (const float*)d_in[1];
    const float* W   = (const float*)d_in[2];
    const float* bbp = (const float*)d_in[3];
    const float* hhp = (const float*)d_in[4];
    const float* d1w = (const float*)d_in[5];
    const float* d1b = (const float*)d_in[6];
    const float* d2w = (const float*)d_in[7];
    const float* d2b = (const float*)d_in[8];
    const float* fw  = (const float*)d_in[9];
    const float* fb  = (const float*)d_in[10];
    float* out = (float*)d_out;

    const int B = in_sizes[0] / NF;
    const int grid = (B + BPB - 1) / BPB;
    afm_wave_kernel<<<grid, 256, 0, stream>>>(x, emb, W, bbp, hhp,
                                              d1w, d1b, d2w, d2b, fw, fb, out, B);
}